// Round 1
// baseline (681.538 us; speedup 1.0000x reference)
//
#include <hip/hip_runtime.h>

#define N_DEC  24
#define IN_DIM 768
#define HID    128
#define ODIM   99136
#define BATCH  64

// ---------------- Kernel A: h[n][b][t] = relu(x[b,:] . w1[n,:,t] + b1[n,t]) ----
__global__ __launch_bounds__(128) void gen_h_kernel(
    const float* __restrict__ x, const float* __restrict__ w1,
    const float* __restrict__ b1, float* __restrict__ h)
{
    const int nb = blockIdx.x;            // n*64 + b
    const int n  = nb >> 6;
    const int b  = nb & 63;
    const int t  = threadIdx.x;           // 0..127 (one hid unit each)

    __shared__ float xs[IN_DIM];
    #pragma unroll
    for (int i = 0; i < IN_DIM / 128; ++i)
        xs[t + i * 128] = x[b * IN_DIM + t + i * 128];
    __syncthreads();

    const float* w = w1 + (size_t)n * IN_DIM * HID + t;
    float acc = 0.f;
    #pragma unroll 8
    for (int i = 0; i < IN_DIM; ++i)
        acc = fmaf(xs[i], w[(size_t)i * HID], acc);

    acc += b1[n * HID + t];
    h[((size_t)nb << 7) + t] = fmaxf(acc, 0.f);
}

// ---------------- Kernel B: out[n][b][o] = h[n][b][:] . w2[n][:][o] + b2[n][o] -
// Block: 256 threads. Tile: 64 batches x 128 outputs.
// Thread (to = tid&31, tb = tid>>5): outputs o = ob + to*4 .. +3, batches tb*8..tb*8+7.
__global__ __launch_bounds__(256) void gen_out_kernel(
    const float* __restrict__ h, const float* __restrict__ w2,
    const float* __restrict__ b2, float* __restrict__ out)
{
    const int n  = blockIdx.y;
    const long ob = (long)blockIdx.x * 128;
    const int to = threadIdx.x & 31;
    const int tb = threadIdx.x >> 5;
    const long o = ob + to * 4;

    __shared__ float hs[BATCH][HID];      // 32 KB

    // Cooperative load of the h panel for this n: 8192 floats = 2048 float4.
    {
        const float4* hp = (const float4*)(h + (size_t)n * BATCH * HID);
        float4* hv = (float4*)&hs[0][0];
        #pragma unroll
        for (int k = 0; k < 8; ++k)
            hv[threadIdx.x + k * 256] = hp[threadIdx.x + k * 256];
    }
    __syncthreads();

    if (o >= ODIM) return;                // partial last tile (width 64)

    const float* wp = w2 + (size_t)n * HID * ODIM + o;

    float4 acc[8];
    #pragma unroll
    for (int j = 0; j < 8; ++j) acc[j] = make_float4(0.f, 0.f, 0.f, 0.f);

    for (int hh = 0; hh < HID; hh += 4) {
        const float4 wv0 = *(const float4*)(wp + (size_t)(hh + 0) * ODIM);
        const float4 wv1 = *(const float4*)(wp + (size_t)(hh + 1) * ODIM);
        const float4 wv2 = *(const float4*)(wp + (size_t)(hh + 2) * ODIM);
        const float4 wv3 = *(const float4*)(wp + (size_t)(hh + 3) * ODIM);
        #pragma unroll
        for (int j = 0; j < 8; ++j) {
            const float4 hb = *(const float4*)&hs[tb * 8 + j][hh];
            acc[j].x = fmaf(hb.x, wv0.x, acc[j].x);
            acc[j].y = fmaf(hb.x, wv0.y, acc[j].y);
            acc[j].z = fmaf(hb.x, wv0.z, acc[j].z);
            acc[j].w = fmaf(hb.x, wv0.w, acc[j].w);
            acc[j].x = fmaf(hb.y, wv1.x, acc[j].x);
            acc[j].y = fmaf(hb.y, wv1.y, acc[j].y);
            acc[j].z = fmaf(hb.y, wv1.z, acc[j].z);
            acc[j].w = fmaf(hb.y, wv1.w, acc[j].w);
            acc[j].x = fmaf(hb.z, wv2.x, acc[j].x);
            acc[j].y = fmaf(hb.z, wv2.y, acc[j].y);
            acc[j].z = fmaf(hb.z, wv2.z, acc[j].z);
            acc[j].w = fmaf(hb.z, wv2.w, acc[j].w);
            acc[j].x = fmaf(hb.w, wv3.x, acc[j].x);
            acc[j].y = fmaf(hb.w, wv3.y, acc[j].y);
            acc[j].z = fmaf(hb.w, wv3.z, acc[j].z);
            acc[j].w = fmaf(hb.w, wv3.w, acc[j].w);
        }
    }

    const float4 bb = *(const float4*)(b2 + (size_t)n * ODIM + o);
    #pragma unroll
    for (int j = 0; j < 8; ++j) {
        float4 r;
        r.x = acc[j].x + bb.x;
        r.y = acc[j].y + bb.y;
        r.z = acc[j].z + bb.z;
        r.w = acc[j].w + bb.w;
        const size_t oi = ((size_t)n * BATCH + tb * 8 + j) * ODIM + o;
        *(float4*)(out + oi) = r;
    }
}

extern "C" void kernel_launch(void* const* d_in, const int* in_sizes, int n_in,
                              void* d_out, int out_size, void* d_ws, size_t ws_size,
                              hipStream_t stream)
{
    const float* x  = (const float*)d_in[0];
    const float* w1 = (const float*)d_in[1];
    const float* b1 = (const float*)d_in[2];
    const float* w2 = (const float*)d_in[3];
    const float* b2 = (const float*)d_in[4];
    float* out = (float*)d_out;
    float* h   = (float*)d_ws;            // 24*64*128 floats = 3 MB scratch

    gen_h_kernel<<<dim3(N_DEC * BATCH), dim3(128), 0, stream>>>(x, w1, b1, h);

    dim3 grid((ODIM + 127) / 128, N_DEC);
    gen_out_kernel<<<grid, dim3(256), 0, stream>>>(h, w2, b2, out);
}

// Round 2
// 581.201 us; speedup vs baseline: 1.1726x; 1.1726x over previous
//
#include <hip/hip_runtime.h>
#include <hip/hip_bf16.h>

#define N_DEC  24
#define IN_DIM 768
#define HID    128
#define ODIM   99136
#define BATCH  64

typedef __attribute__((ext_vector_type(8))) short bf16x8;
typedef __attribute__((ext_vector_type(4))) float f32x4;

static __device__ __forceinline__ short f2bf_bits(float f) {
    union { __hip_bfloat16 b; short s; } u;
    u.b = __float2bfloat16(f);
    return u.s;
}

// ---------------- Kernel A: h_bf16[n][b][t] = bf16(relu(x[b,:] . w1[n,:,t] + b1[n,t]))
__global__ __launch_bounds__(128) void gen_h_kernel(
    const float* __restrict__ x, const float* __restrict__ w1,
    const float* __restrict__ b1, __hip_bfloat16* __restrict__ h)
{
    const int nb = blockIdx.x;            // n*64 + b
    const int n  = nb >> 6;
    const int b  = nb & 63;
    const int t  = threadIdx.x;           // 0..127

    __shared__ float xs[IN_DIM];
    #pragma unroll
    for (int i = 0; i < IN_DIM / 128; ++i)
        xs[t + i * 128] = x[b * IN_DIM + t + i * 128];
    __syncthreads();

    const float* w = w1 + (size_t)n * IN_DIM * HID + t;
    float acc = 0.f;
    #pragma unroll 8
    for (int i = 0; i < IN_DIM; ++i)
        acc = fmaf(xs[i], w[(size_t)i * HID], acc);

    acc += b1[n * HID + t];
    h[((size_t)nb << 7) + t] = __float2bfloat16(fmaxf(acc, 0.f));
}

// ---------------- Kernel B: out[n][b][o] = h[n][b][:] . w2[n][:][o] + b2[n][o]
// MFMA 16x16x32 bf16. Block = 256 threads = 4 waves; block tile = 64 b x 64 o.
// Each wave: full 64 batches x 16 outputs. A (h) loaded bf16 direct to fragments;
// B (w2) streamed f32 -> bf16 fragments in registers. No LDS.
__global__ __launch_bounds__(256) void gen_out_mfma(
    const __hip_bfloat16* __restrict__ h, const float* __restrict__ w2,
    const float* __restrict__ b2, float* __restrict__ out)
{
    const int n    = blockIdx.y;
    const int wave = threadIdx.x >> 6;    // 0..3
    const int lane = threadIdx.x & 63;
    const int lr   = lane & 15;           // col-in-tile (o) / row-in-tile (b) for A
    const int lg   = lane >> 4;           // k-octet selector
    const size_t o = (size_t)blockIdx.x * 64 + wave * 16 + lr;

    // ---- B stream: issue all 32 w2 loads first (HBM, deepest latency)
    const float* wl = w2 + (size_t)n * HID * ODIM + (size_t)(lg * 8) * ODIM + o;
    float bv[4][8];
    #pragma unroll
    for (int ks = 0; ks < 4; ++ks)
        #pragma unroll
        for (int i = 0; i < 8; ++i)
            bv[ks][i] = wl[(size_t)(ks * 32 + i) * ODIM];

    // ---- A fragments: h[n][64][128] bf16 (L2-hot), 4 m-tiles x 4 k-steps
    const short* hb = (const short*)(h + ((size_t)n * BATCH) * HID);
    bf16x8 a[4][4];
    #pragma unroll
    for (int mt = 0; mt < 4; ++mt)
        #pragma unroll
        for (int ks = 0; ks < 4; ++ks)
            a[mt][ks] = *(const bf16x8*)(hb + (mt * 16 + lr) * HID + ks * 32 + lg * 8);

    // ---- MFMA: acc[mt] over k
    f32x4 acc[4] = {f32x4{0,0,0,0}, f32x4{0,0,0,0}, f32x4{0,0,0,0}, f32x4{0,0,0,0}};
    #pragma unroll
    for (int ks = 0; ks < 4; ++ks) {
        bf16x8 bfrag;
        #pragma unroll
        for (int i = 0; i < 8; ++i)
            bfrag[i] = f2bf_bits(bv[ks][i]);
        #pragma unroll
        for (int mt = 0; mt < 4; ++mt)
            acc[mt] = __builtin_amdgcn_mfma_f32_16x16x32_bf16(a[mt][ks], bfrag, acc[mt], 0, 0, 0);
    }

    // ---- Epilogue: D row = mt*16 + lg*4 + r (batch), col = o
    const float bias = b2[(size_t)n * ODIM + o];
    float* ob = out + ((size_t)n * BATCH) * ODIM + o;
    #pragma unroll
    for (int mt = 0; mt < 4; ++mt)
        #pragma unroll
        for (int r = 0; r < 4; ++r)
            ob[(size_t)(mt * 16 + lg * 4 + r) * ODIM] = acc[mt][r] + bias;
}

extern "C" void kernel_launch(void* const* d_in, const int* in_sizes, int n_in,
                              void* d_out, int out_size, void* d_ws, size_t ws_size,
                              hipStream_t stream)
{
    const float* x  = (const float*)d_in[0];
    const float* w1 = (const float*)d_in[1];
    const float* b1 = (const float*)d_in[2];
    const float* w2 = (const float*)d_in[3];
    const float* b2 = (const float*)d_in[4];
    float* out = (float*)d_out;
    __hip_bfloat16* hbf = (__hip_bfloat16*)d_ws;   // 24*64*128 bf16 = 384 KB

    gen_h_kernel<<<dim3(N_DEC * BATCH), dim3(128), 0, stream>>>(x, w1, b1, hbf);

    gen_out_mfma<<<dim3(ODIM / 64, N_DEC), dim3(256), 0, stream>>>(hbf, w2, b2, out);
}

// Round 3
// 482.001 us; speedup vs baseline: 1.4140x; 1.2058x over previous
//
#include <hip/hip_runtime.h>
#include <hip/hip_bf16.h>

#define N_DEC  24
#define IN_DIM 768
#define HID    128
#define ODIM   99136
#define BATCH  64

typedef __attribute__((ext_vector_type(8))) short bf16x8;
typedef __attribute__((ext_vector_type(4))) float f32x4;

static __device__ __forceinline__ short f2bf_bits(float f) {
    union { __hip_bfloat16 b; short s; } u;
    u.b = __float2bfloat16(f);
    return u.s;
}

// ---------------- Kernel A ----------------
// h[b][t] = relu(x[b,:] . w1[n,:,t] + b1[n,t]), stored bf16 in MFMA-A-fragment
// swizzled order: per n, chunk c = (ks*4+mt)*64 + lane (16 B each) holds the
// bf16x8 that lane needs for a[mt][ks]:
//   element i of chunk = h[b = mt*16 + (lane&15)][k = ks*32 + (lane>>4)*8 + i]
__global__ __launch_bounds__(128) void gen_h_kernel(
    const float* __restrict__ x, const float* __restrict__ w1,
    const float* __restrict__ b1, __hip_bfloat16* __restrict__ hswz)
{
    const int nb = blockIdx.x;            // n*64 + b
    const int n  = nb >> 6;
    const int b  = nb & 63;
    const int t  = threadIdx.x;           // k index, 0..127

    __shared__ float xs[IN_DIM];
    #pragma unroll
    for (int i = 0; i < IN_DIM / 128; ++i)
        xs[t + i * 128] = x[b * IN_DIM + t + i * 128];
    __syncthreads();

    const float* w = w1 + (size_t)n * IN_DIM * HID + t;
    float a0 = 0.f, a1 = 0.f, a2 = 0.f, a3 = 0.f;
    #pragma unroll 4
    for (int i = 0; i < IN_DIM; i += 4) {
        a0 = fmaf(xs[i + 0], w[(size_t)(i + 0) * HID], a0);
        a1 = fmaf(xs[i + 1], w[(size_t)(i + 1) * HID], a1);
        a2 = fmaf(xs[i + 2], w[(size_t)(i + 2) * HID], a2);
        a3 = fmaf(xs[i + 3], w[(size_t)(i + 3) * HID], a3);
    }
    float acc = (a0 + a1) + (a2 + a3) + b1[n * HID + t];
    acc = fmaxf(acc, 0.f);

    // swizzled write position
    const int mt = b >> 4, lr = b & 15;
    const int ks = t >> 5, lg = (t >> 3) & 3, ii = t & 7;
    const size_t idx = (size_t)n * 8192
                     + (size_t)(((ks * 4 + mt) * 64) + lg * 16 + lr) * 8 + ii;
    hswz[idx] = __float2bfloat16(acc);
}

// ---------------- Kernel B ----------------
// out[n][b][o] = h[n][b][:] . w2[n][:][o] + b2[n][o]
// MFMA 16x16x32 bf16. Block = 256 threads = 4 waves; block tile 64 b x 64 o.
// Wave: 64 batches x 16 outputs. A frags: coalesced 1KB loads from swizzled h
// (L1/L2-hot). B (w2): streamed f32 -> bf16 in registers, each element read once.
__global__ __launch_bounds__(256, 3) void gen_out_mfma(
    const __hip_bfloat16* __restrict__ hswz, const float* __restrict__ w2,
    const float* __restrict__ b2, float* __restrict__ out)
{
    const int n    = blockIdx.y;
    const int wave = threadIdx.x >> 6;    // 0..3
    const int lane = threadIdx.x & 63;
    const int lr   = lane & 15;
    const int lg   = lane >> 4;
    const size_t o = (size_t)blockIdx.x * 64 + wave * 16 + lr;

    // ---- B stream: issue all 32 w2 loads first (HBM, deepest latency)
    const float* wl = w2 + (size_t)n * HID * ODIM + (size_t)(lg * 8) * ODIM + o;
    float bv[4][8];
    #pragma unroll
    for (int ks = 0; ks < 4; ++ks)
        #pragma unroll
        for (int i = 0; i < 8; ++i)
            bv[ks][i] = wl[(size_t)(ks * 32 + i) * ODIM];

    // ---- A fragments: perfectly coalesced (chunk c = (ks*4+mt)*64 + lane)
    const bf16x8* ha = (const bf16x8*)hswz + (size_t)n * 1024 + lane;
    bf16x8 a[4][4];
    #pragma unroll
    for (int mt = 0; mt < 4; ++mt)
        #pragma unroll
        for (int ks = 0; ks < 4; ++ks)
            a[mt][ks] = ha[(ks * 4 + mt) * 64];

    // ---- MFMA
    f32x4 acc[4] = {f32x4{0,0,0,0}, f32x4{0,0,0,0}, f32x4{0,0,0,0}, f32x4{0,0,0,0}};
    #pragma unroll
    for (int ks = 0; ks < 4; ++ks) {
        bf16x8 bfrag;
        #pragma unroll
        for (int i = 0; i < 8; ++i)
            bfrag[i] = f2bf_bits(bv[ks][i]);
        #pragma unroll
        for (int mt = 0; mt < 4; ++mt)
            acc[mt] = __builtin_amdgcn_mfma_f32_16x16x32_bf16(a[mt][ks], bfrag, acc[mt], 0, 0, 0);
    }

    // ---- Epilogue: D row = mt*16 + lg*4 + r (batch), col = o
    const float bias = b2[(size_t)n * ODIM + o];
    float* ob = out + ((size_t)n * BATCH) * ODIM + o;
    #pragma unroll
    for (int mt = 0; mt < 4; ++mt)
        #pragma unroll
        for (int r = 0; r < 4; ++r)
            ob[(size_t)(mt * 16 + lg * 4 + r) * ODIM] = acc[mt][r] + bias;
}

extern "C" void kernel_launch(void* const* d_in, const int* in_sizes, int n_in,
                              void* d_out, int out_size, void* d_ws, size_t ws_size,
                              hipStream_t stream)
{
    const float* x  = (const float*)d_in[0];
    const float* w1 = (const float*)d_in[1];
    const float* b1 = (const float*)d_in[2];
    const float* w2 = (const float*)d_in[3];
    const float* b2 = (const float*)d_in[4];
    float* out = (float*)d_out;
    __hip_bfloat16* hbf = (__hip_bfloat16*)d_ws;   // 24*8192 bf16 = 384 KB (swizzled)

    gen_h_kernel<<<dim3(N_DEC * BATCH), dim3(128), 0, stream>>>(x, w1, b1, hbf);

    gen_out_mfma<<<dim3(ODIM / 64, N_DEC), dim3(256), 0, stream>>>(hbf, w2, b2, out);
}

// Round 4
// 398.545 us; speedup vs baseline: 1.7101x; 1.2094x over previous
//
#include <hip/hip_runtime.h>
#include <hip/hip_bf16.h>

#define N_DEC  24
#define IN_DIM 768
#define HID    128
#define ODIM   99136
#define BATCH  64
#define OTILE  256
#define NXBLK  ((ODIM + OTILE - 1) / OTILE)   // 388 (last block: 64 valid cols)

typedef __attribute__((ext_vector_type(8))) short bf16x8;
typedef __attribute__((ext_vector_type(4))) float f32x4;

static __device__ __forceinline__ short f2bf_bits(float f) {
    union { __hip_bfloat16 b; short s; } u;
    u.b = __float2bfloat16(f);
    return u.s;
}

static __device__ __forceinline__ void gload_lds16(const float* src, float* dst) {
    __builtin_amdgcn_global_load_lds(
        (const __attribute__((address_space(1))) void*)src,
        (__attribute__((address_space(3))) void*)dst, 16, 0, 0);
}

// ---------------- Kernel A ----------------
// h stored bf16 in MFMA-A-fragment swizzled order (validated R3):
// per n, chunk c = (ks*4+mt)*64 + lane holds lane's bf16x8 for a[mt][ks].
__global__ __launch_bounds__(128) void gen_h_kernel(
    const float* __restrict__ x, const float* __restrict__ w1,
    const float* __restrict__ b1, __hip_bfloat16* __restrict__ hswz)
{
    const int nb = blockIdx.x;
    const int n  = nb >> 6;
    const int b  = nb & 63;
    const int t  = threadIdx.x;

    __shared__ float xs[IN_DIM];
    #pragma unroll
    for (int i = 0; i < IN_DIM / 128; ++i)
        xs[t + i * 128] = x[b * IN_DIM + t + i * 128];
    __syncthreads();

    const float* w = w1 + (size_t)n * IN_DIM * HID + t;
    float a0 = 0.f, a1 = 0.f, a2 = 0.f, a3 = 0.f;
    #pragma unroll 4
    for (int i = 0; i < IN_DIM; i += 4) {
        a0 = fmaf(xs[i + 0], w[(size_t)(i + 0) * HID], a0);
        a1 = fmaf(xs[i + 1], w[(size_t)(i + 1) * HID], a1);
        a2 = fmaf(xs[i + 2], w[(size_t)(i + 2) * HID], a2);
        a3 = fmaf(xs[i + 3], w[(size_t)(i + 3) * HID], a3);
    }
    float acc = (a0 + a1) + (a2 + a3) + b1[n * HID + t];
    acc = fmaxf(acc, 0.f);

    const int mt = b >> 4, lr = b & 15;
    const int ks = t >> 5, lg = (t >> 3) & 3, ii = t & 7;
    const size_t idx = (size_t)n * 8192
                     + (size_t)(((ks * 4 + mt) * 64) + lg * 16 + lr) * 8 + ii;
    hswz[idx] = __float2bfloat16(acc);
}

// ---------------- Kernel B ----------------
// out[n][b][o] = h[n][b][:] . w2[n][:][o] + b2[n][o]
// 4 waves, o-tile 256 (wave w owns cols w*64..w*64+63, 4 subtiles of 16).
// w2 staged f32 into LDS via global_load_lds x16 (double-buffered, 32-row
// chunks, XOR-swizzled cols: phys = logical ^ ((row>>3)&3)<<3 dwords).
__global__ __launch_bounds__(256, 2) void gen_out_mfma(
    const __hip_bfloat16* __restrict__ hswz, const float* __restrict__ w2,
    const float* __restrict__ b2, float* __restrict__ out)
{
    const int n    = blockIdx.y;
    const int tid  = threadIdx.x;
    const int wave = tid >> 6;
    const int lane = tid & 63;
    const int lr   = lane & 15;
    const int lg   = lane >> 4;
    const long oblk = (long)blockIdx.x * OTILE;

    __shared__ float lds[2][32][256];     // 64 KB

    const float* w2n = w2 + (size_t)n * HID * ODIM;

    // ---- A fragments (swizzled h, 1KB coalesced loads, L1/L2-hot)
    const bf16x8* ha = (const bf16x8*)hswz + (size_t)n * 1024 + lane;
    bf16x8 a[4][4];
    #pragma unroll
    for (int mt = 0; mt < 4; ++mt)
        #pragma unroll
        for (int ks = 0; ks < 4; ++ks)
            a[mt][ks] = ha[(ks * 4 + mt) * 64];

    // ---- bias (clamped for tail block; unused lanes guarded at store)
    float bias[4];
    #pragma unroll
    for (int tt = 0; tt < 4; ++tt) {
        long c = oblk + wave * 64 + tt * 16 + lr;
        if (c > ODIM - 1) c = ODIM - 1;
        bias[tt] = b2[(size_t)n * ODIM + c];
    }

    // ---- staging: chunk ks (rows ks*32..+31) into lds[buf]; wave stages its 8 rows
    auto stage = [&](int buf, int ks) {
        #pragma unroll
        for (int p = 0; p < 8; ++p) {
            const int r   = wave * 8 + p;
            const int swz = ((r >> 3) & 3) << 3;          // dword-col XOR, bits 3-4
            long col = oblk + ((lane * 4) ^ swz);
            if (col > ODIM - 4) col = ODIM - 4;           // 16B-aligned clamp
            gload_lds16(w2n + (size_t)(ks * 32 + r) * ODIM + col, &lds[buf][r][0]);
        }
    };

    f32x4 acc[4][4];
    #pragma unroll
    for (int tt = 0; tt < 4; ++tt)
        #pragma unroll
        for (int mt = 0; mt < 4; ++mt)
            acc[tt][mt] = f32x4{0.f, 0.f, 0.f, 0.f};

    stage(0, 0);

    #pragma unroll
    for (int ks = 0; ks < 4; ++ks) {
        __builtin_amdgcn_s_barrier();     // prev chunk's LDS reads finished everywhere
        if (ks < 3) {
            stage((ks + 1) & 1, ks + 1);  // prefetch next chunk (stays in flight)
            asm volatile("s_waitcnt vmcnt(8)" ::: "memory");   // chunk ks landed
        } else {
            asm volatile("s_waitcnt vmcnt(0)" ::: "memory");
        }
        __builtin_amdgcn_s_barrier();     // chunk ks visible to all waves

        const int buf = ks & 1;
        #pragma unroll
        for (int tt = 0; tt < 4; ++tt) {
            const int csw = (wave * 64 + tt * 16 + lr) ^ (lg << 3);
            const float* lp = &lds[buf][lg * 8][csw];
            float bv[8];
            #pragma unroll
            for (int i = 0; i < 8; ++i)
                bv[i] = lp[(size_t)i * 256];              // ds_read_b32 offset:i*1024
            bf16x8 bf;
            #pragma unroll
            for (int i = 0; i < 8; ++i)
                bf[i] = f2bf_bits(bv[i]);
            #pragma unroll
            for (int mt = 0; mt < 4; ++mt)
                acc[tt][mt] = __builtin_amdgcn_mfma_f32_16x16x32_bf16(
                                  a[mt][ks], bf, acc[tt][mt], 0, 0, 0);
        }
    }

    // ---- epilogue: D row = mt*16 + lg*4 + r (batch), col = o
    float* ob = out + ((size_t)n * BATCH) * ODIM;
    #pragma unroll
    for (int tt = 0; tt < 4; ++tt) {
        const long o = oblk + wave * 64 + tt * 16 + lr;
        if (o < ODIM) {
            #pragma unroll
            for (int mt = 0; mt < 4; ++mt)
                #pragma unroll
                for (int r = 0; r < 4; ++r)
                    ob[(size_t)(mt * 16 + lg * 4 + r) * ODIM + o] = acc[tt][mt][r] + bias[tt];
        }
    }
}

extern "C" void kernel_launch(void* const* d_in, const int* in_sizes, int n_in,
                              void* d_out, int out_size, void* d_ws, size_t ws_size,
                              hipStream_t stream)
{
    const float* x  = (const float*)d_in[0];
    const float* w1 = (const float*)d_in[1];
    const float* b1 = (const float*)d_in[2];
    const float* w2 = (const float*)d_in[3];
    const float* b2 = (const float*)d_in[4];
    float* out = (float*)d_out;
    __hip_bfloat16* hbf = (__hip_bfloat16*)d_ws;   // 384 KB swizzled h

    gen_h_kernel<<<dim3(N_DEC * BATCH), dim3(128), 0, stream>>>(x, w1, b1, hbf);

    gen_out_mfma<<<dim3(NXBLK, N_DEC), dim3(256), 0, stream>>>(hbf, w2, b2, out);
}

// Round 5
// 376.530 us; speedup vs baseline: 1.8101x; 1.0585x over previous
//
#include <hip/hip_runtime.h>
#include <hip/hip_bf16.h>

#define N_DEC  24
#define IN_DIM 768
#define HID    128
#define ODIM   99136
#define BATCH  64
#define OTILE  256
#define NXBLK  ((ODIM + OTILE - 1) / OTILE)   // 388 (last block: 64 valid cols)

typedef __attribute__((ext_vector_type(8))) short bf16x8;
typedef __attribute__((ext_vector_type(4))) float f32x4;

static __device__ __forceinline__ short f2bf_bits(float f) {
    union { __hip_bfloat16 b; short s; } u;
    u.b = __float2bfloat16(f);
    return u.s;
}

static __device__ __forceinline__ void gload_lds16(const float* src, float* dst) {
    __builtin_amdgcn_global_load_lds(
        (const __attribute__((address_space(1))) void*)src,
        (__attribute__((address_space(3))) void*)dst, 16, 0, 0);
}

// ---------------- Kernel A ----------------
// h stored bf16 in MFMA-A-fragment swizzled order (validated R3/R4):
// per n, chunk c = (ks*4+mt)*64 + lane holds lane's bf16x8 for a[mt][ks].
__global__ __launch_bounds__(128) void gen_h_kernel(
    const float* __restrict__ x, const float* __restrict__ w1,
    const float* __restrict__ b1, __hip_bfloat16* __restrict__ hswz)
{
    const int nb = blockIdx.x;
    const int n  = nb >> 6;
    const int b  = nb & 63;
    const int t  = threadIdx.x;

    __shared__ float xs[IN_DIM];
    #pragma unroll
    for (int i = 0; i < IN_DIM / 128; ++i)
        xs[t + i * 128] = x[b * IN_DIM + t + i * 128];
    __syncthreads();

    const float* w = w1 + (size_t)n * IN_DIM * HID + t;
    float a0 = 0.f, a1 = 0.f, a2 = 0.f, a3 = 0.f;
    #pragma unroll 4
    for (int i = 0; i < IN_DIM; i += 4) {
        a0 = fmaf(xs[i + 0], w[(size_t)(i + 0) * HID], a0);
        a1 = fmaf(xs[i + 1], w[(size_t)(i + 1) * HID], a1);
        a2 = fmaf(xs[i + 2], w[(size_t)(i + 2) * HID], a2);
        a3 = fmaf(xs[i + 3], w[(size_t)(i + 3) * HID], a3);
    }
    float acc = (a0 + a1) + (a2 + a3) + b1[n * HID + t];
    acc = fmaxf(acc, 0.f);

    const int mt = b >> 4, lr = b & 15;
    const int ks = t >> 5, lg = (t >> 3) & 3, ii = t & 7;
    const size_t idx = (size_t)n * 8192
                     + (size_t)(((ks * 4 + mt) * 64) + lg * 16 + lr) * 8 + ii;
    hswz[idx] = __float2bfloat16(acc);
}

// ---------------- Kernel B ----------------
// out[n][b][o] = h[n][b][:] . w2[n][:][o] + b2[n][o]
// 4 waves, o-tile 256. w2 staged f32 via global_load_lds x16 (double-buffered
// 32-row chunks, XOR-swizzled cols). Epilogue: per-wave LDS transpose ->
// dwordx4 stores with 256-B contiguous segments.
__global__ __launch_bounds__(256, 2) void gen_out_mfma(
    const __hip_bfloat16* __restrict__ hswz, const float* __restrict__ w2,
    const float* __restrict__ b2, float* __restrict__ out)
{
    const int n    = blockIdx.y;
    const int tid  = threadIdx.x;
    const int wave = tid >> 6;
    const int lane = tid & 63;
    const int lr   = lane & 15;
    const int lg   = lane >> 4;
    const long oblk = (long)blockIdx.x * OTILE;

    __shared__ float lds[2][32][256];     // 64 KB

    const float* w2n = w2 + (size_t)n * HID * ODIM;

    // ---- staging: chunk ks (rows ks*32..+31) into lds[buf]; wave stages its 8 rows
    auto stage = [&](int buf, int ks) {
        #pragma unroll
        for (int p = 0; p < 8; ++p) {
            const int r   = wave * 8 + p;
            const int swz = ((r >> 3) & 3) << 3;          // dword-col XOR, bits 3-4
            long col = oblk + ((lane * 4) ^ swz);
            if (col > ODIM - 4) col = ODIM - 4;           // 16B-aligned clamp
            gload_lds16(w2n + (size_t)(ks * 32 + r) * ODIM + col, &lds[buf][r][0]);
        }
    };

    stage(0, 0);                          // issue first chunk ASAP (HBM latency)

    // ---- A fragments (swizzled h, 1KB coalesced loads, L1/L2-hot)
    const bf16x8* ha = (const bf16x8*)hswz + (size_t)n * 1024 + lane;
    bf16x8 a[4][4];
    #pragma unroll
    for (int mt = 0; mt < 4; ++mt)
        #pragma unroll
        for (int ks = 0; ks < 4; ++ks)
            a[mt][ks] = ha[(ks * 4 + mt) * 64];

    // ---- bias as coalesced float4 (post-transpose layout), clamped for tail
    f32x4 bias4;
    const long ocol = oblk + wave * 64 + lr * 4;
    {
        long c = ocol;
        if (c > ODIM - 4) c = ODIM - 4;
        bias4 = *(const f32x4*)(b2 + (size_t)n * ODIM + c);
    }

    f32x4 acc[4][4];
    #pragma unroll
    for (int tt = 0; tt < 4; ++tt)
        #pragma unroll
        for (int mt = 0; mt < 4; ++mt)
            acc[tt][mt] = f32x4{0.f, 0.f, 0.f, 0.f};

    #pragma unroll
    for (int ks = 0; ks < 4; ++ks) {
        __builtin_amdgcn_s_barrier();     // prev chunk's LDS reads finished everywhere
        if (ks < 3) {
            stage((ks + 1) & 1, ks + 1);  // prefetch next chunk (stays in flight)
            asm volatile("s_waitcnt vmcnt(8)" ::: "memory");   // chunk ks landed
        } else {
            asm volatile("s_waitcnt vmcnt(0)" ::: "memory");
        }
        __builtin_amdgcn_s_barrier();     // chunk ks visible to all waves

        const int buf = ks & 1;
        #pragma unroll
        for (int tt = 0; tt < 4; ++tt) {
            const int csw = (wave * 64 + tt * 16 + lr) ^ (lg << 3);
            const float* lp = &lds[buf][lg * 8][csw];
            float bv[8];
            #pragma unroll
            for (int i = 0; i < 8; ++i)
                bv[i] = lp[(size_t)i * 256];
            bf16x8 bf;
            #pragma unroll
            for (int i = 0; i < 8; ++i)
                bf[i] = f2bf_bits(bv[i]);
            #pragma unroll
            for (int mt = 0; mt < 4; ++mt)
                acc[tt][mt] = __builtin_amdgcn_mfma_f32_16x16x32_bf16(
                                  a[mt][ks], bf, acc[tt][mt], 0, 0, 0);
        }
    }

    // ---- epilogue: per-wave transpose through buf0 slice (free after ks=3's
    // first barrier), then 256-B-segment dwordx4 stores.
    float* tb = &lds[0][0][0] + wave * 1024;        // private 4 KB per wave
    float* ob = out + ((size_t)n * BATCH) * ODIM;
    const int rr = lane >> 4;                       // 0..3 (row-in-quad)

    #pragma unroll
    for (int mt = 0; mt < 4; ++mt) {
        // write 16 scalars: row (lg*4+r), col (tt*16+lr) within 16x64 tile
        #pragma unroll
        for (int tt = 0; tt < 4; ++tt)
            #pragma unroll
            for (int r = 0; r < 4; ++r)
                tb[(lg * 4 + r) * 64 + tt * 16 + lr] = acc[tt][mt][r];
        // read transposed: row j*4+rr, 4 consecutive cols lr*4; wide store
        #pragma unroll
        for (int j = 0; j < 4; ++j) {
            f32x4 v = *(const f32x4*)&tb[(j * 4 + rr) * 64 + lr * 4];
            v += bias4;
            if (ocol <= ODIM - 4)
                *(f32x4*)(ob + (size_t)(mt * 16 + j * 4 + rr) * ODIM + ocol) = v;
        }
    }
}

extern "C" void kernel_launch(void* const* d_in, const int* in_sizes, int n_in,
                              void* d_out, int out_size, void* d_ws, size_t ws_size,
                              hipStream_t stream)
{
    const float* x  = (const float*)d_in[0];
    const float* w1 = (const float*)d_in[1];
    const float* b1 = (const float*)d_in[2];
    const float* w2 = (const float*)d_in[3];
    const float* b2 = (const float*)d_in[4];
    float* out = (float*)d_out;
    __hip_bfloat16* hbf = (__hip_bfloat16*)d_ws;   // 384 KB swizzled h

    gen_h_kernel<<<dim3(N_DEC * BATCH), dim3(128), 0, stream>>>(x, w1, b1, hbf);

    gen_out_mfma<<<dim3(NXBLK, N_DEC), dim3(256), 0, stream>>>(hbf, w2, b2, out);
}

// Round 6
// 372.826 us; speedup vs baseline: 1.8280x; 1.0099x over previous
//
#include <hip/hip_runtime.h>
#include <hip/hip_bf16.h>

#define N_DEC  24
#define IN_DIM 768
#define HID    128
#define ODIM   99136
#define BATCH  64
#define OTILE  256
#define NXBLK  ((ODIM + OTILE - 1) / OTILE)   // 388 (last block: 64 valid cols)

typedef __attribute__((ext_vector_type(8))) short bf16x8;
typedef __attribute__((ext_vector_type(4))) float f32x4;

static __device__ __forceinline__ short f2bf_bits(float f) {
    union { __hip_bfloat16 b; short s; } u;
    u.b = __float2bfloat16(f);
    return u.s;
}

static __device__ __forceinline__ void gload_lds16(const float* src, float* dst) {
    __builtin_amdgcn_global_load_lds(
        (const __attribute__((address_space(1))) void*)src,
        (__attribute__((address_space(3))) void*)dst, 16, 0, 0);
}

// ---------------- Kernel A ----------------
// h stored bf16 in MFMA-A-fragment swizzled order (validated R3-R5):
// per n, chunk c = (ks*4+mt)*64 + lane holds lane's bf16x8 for a[mt][ks].
__global__ __launch_bounds__(128) void gen_h_kernel(
    const float* __restrict__ x, const float* __restrict__ w1,
    const float* __restrict__ b1, __hip_bfloat16* __restrict__ hswz)
{
    const int nb = blockIdx.x;
    const int n  = nb >> 6;
    const int b  = nb & 63;
    const int t  = threadIdx.x;

    __shared__ float xs[IN_DIM];
    #pragma unroll
    for (int i = 0; i < IN_DIM / 128; ++i)
        xs[t + i * 128] = x[b * IN_DIM + t + i * 128];
    __syncthreads();

    const float* w = w1 + (size_t)n * IN_DIM * HID + t;
    float a0 = 0.f, a1 = 0.f, a2 = 0.f, a3 = 0.f;
    #pragma unroll 4
    for (int i = 0; i < IN_DIM; i += 4) {
        a0 = fmaf(xs[i + 0], w[(size_t)(i + 0) * HID], a0);
        a1 = fmaf(xs[i + 1], w[(size_t)(i + 1) * HID], a1);
        a2 = fmaf(xs[i + 2], w[(size_t)(i + 2) * HID], a2);
        a3 = fmaf(xs[i + 3], w[(size_t)(i + 3) * HID], a3);
    }
    float acc = (a0 + a1) + (a2 + a3) + b1[n * HID + t];
    acc = fmaxf(acc, 0.f);

    const int mt = b >> 4, lr = b & 15;
    const int ks = t >> 5, lg = (t >> 3) & 3, ii = t & 7;
    const size_t idx = (size_t)n * 8192
                     + (size_t)(((ks * 4 + mt) * 64) + lg * 16 + lr) * 8 + ii;
    hswz[idx] = __float2bfloat16(acc);
}

// ---------------- Kernel B ----------------
// out[n][b][o] = h[n][b][:] . w2[n][:][o] + b2[n][o]
// 4 waves; each wave owns a PRIVATE 64-col slice and stages its own w2 slice:
// lds[buf][wave][32 rows][64 cols] f32, double-buffered. No barriers at all —
// per-wave pipeline with counted vmcnt. Cols XOR-swizzled (2-way = free).
__global__ __launch_bounds__(256, 2) void gen_out_mfma(
    const __hip_bfloat16* __restrict__ hswz, const float* __restrict__ w2,
    const float* __restrict__ b2, float* __restrict__ out)
{
    const int n    = blockIdx.y;
    const int tid  = threadIdx.x;
    const int wave = tid >> 6;
    const int lane = tid & 63;
    const int lr   = lane & 15;
    const int lg   = lane >> 4;
    const long oblk = (long)blockIdx.x * OTILE;
    const long wcol = oblk + wave * 64;          // wave's column base

    __shared__ float lds[2][4][32][64];          // 64 KB; [buf][wave][row][col]

    const float* w2n = w2 + (size_t)n * HID * ODIM;

    // stage chunk ks (rows ks*32..+31, wave's 64 cols) into lds[buf][wave].
    // inst p: lane l writes byte l*16 at base row 4p -> row 4p+(l>>4), dword (l&15)*4.
    // source col pre-swizzled (G21 both-sides) by ((row>>3)&3)<<3.
    auto stage = [&](int buf, int ks) {
        #pragma unroll
        for (int p = 0; p < 8; ++p) {
            const int r   = 4 * p + lg;
            const int swz = ((r >> 3) & 3) << 3;
            const long col = wcol + ((lr * 4) ^ swz);   // ≤ ODIM-4 even in tail wave0
            long c = col > (long)ODIM - 4 ? (long)ODIM - 4 : col;
            gload_lds16(w2n + (size_t)(ks * 32 + r) * ODIM + c,
                        &lds[buf][wave][4 * p][0]);
        }
    };

    stage(0, 0);                                 // chunk 0 in flight ASAP

    // ---- A fragments (swizzled h, 1KB coalesced loads, L2-hot)
    const bf16x8* ha = (const bf16x8*)hswz + (size_t)n * 1024 + lane;
    bf16x8 a[4][4];
    #pragma unroll
    for (int mt = 0; mt < 4; ++mt)
        #pragma unroll
        for (int ks = 0; ks < 4; ++ks)
            a[mt][ks] = ha[(ks * 4 + mt) * 64];

    // ---- bias as coalesced float4 (post-transpose layout), clamped for tail
    f32x4 bias4;
    const long ocol = wcol + lr * 4;
    {
        long c = ocol > (long)ODIM - 4 ? (long)ODIM - 4 : ocol;
        bias4 = *(const f32x4*)(b2 + (size_t)n * ODIM + c);
    }

    f32x4 acc[4][4];
    #pragma unroll
    for (int tt = 0; tt < 4; ++tt)
        #pragma unroll
        for (int mt = 0; mt < 4; ++mt)
            acc[tt][mt] = f32x4{0.f, 0.f, 0.f, 0.f};

    #pragma unroll
    for (int ks = 0; ks < 4; ++ks) {
        if (ks < 3) {
            stage((ks + 1) & 1, ks + 1);         // next chunk stays in flight
            asm volatile("s_waitcnt vmcnt(8)" ::: "memory");   // chunk ks landed
        } else {
            asm volatile("s_waitcnt vmcnt(0)" ::: "memory");
        }
        __builtin_amdgcn_sched_barrier(0);       // don't hoist ds_read above wait

        const int buf = ks & 1;
        #pragma unroll
        for (int tt = 0; tt < 4; ++tt) {
            const int csw = (tt * 16 + lr) ^ (lg << 3);   // row>>3 == lg for rows lg*8+i
            const float* lp = &lds[buf][wave][lg * 8][csw];
            float bv[8];
            #pragma unroll
            for (int i = 0; i < 8; ++i)
                bv[i] = lp[(size_t)i * 64];
            bf16x8 bf;
            #pragma unroll
            for (int i = 0; i < 8; ++i)
                bf[i] = f2bf_bits(bv[i]);
            #pragma unroll
            for (int mt = 0; mt < 4; ++mt)
                acc[tt][mt] = __builtin_amdgcn_mfma_f32_16x16x32_bf16(
                                  a[mt][ks], bf, acc[tt][mt], 0, 0, 0);
        }
    }

    // ---- epilogue: wave-private transpose through own buf0 slice (dead after
    // ks=2 consumption; wave-private -> program order suffices, no barrier).
    float* tb = &lds[0][wave][0][0];             // 8 KB own slice, need 4 KB
    float* ob = out + ((size_t)n * BATCH) * ODIM;
    const int rr = lane >> 4;                    // 0..3

    #pragma unroll
    for (int mt = 0; mt < 4; ++mt) {
        // write: row = lg*4+r, col = tt*16+lr, swizzled by ((row>>2)&3)<<3 = lg<<3
        #pragma unroll
        for (int tt = 0; tt < 4; ++tt)
            #pragma unroll
            for (int r = 0; r < 4; ++r)
                tb[(lg * 4 + r) * 64 + ((tt * 16 + lr) ^ (lg << 3))] = acc[tt][mt][r];
        // read: row = j*4+rr, cols (lr*4)^((j&3)<<3) .. +3 (aligned chunk), wide store
        #pragma unroll
        for (int j = 0; j < 4; ++j) {
            f32x4 v = *(const f32x4*)&tb[(j * 4 + rr) * 64 + ((lr * 4) ^ ((j & 3) << 3))];
            v += bias4;
            if (ocol <= (long)ODIM - 4)
                *(f32x4*)(ob + (size_t)(mt * 16 + j * 4 + rr) * ODIM + ocol) = v;
        }
    }
}

extern "C" void kernel_launch(void* const* d_in, const int* in_sizes, int n_in,
                              void* d_out, int out_size, void* d_ws, size_t ws_size,
                              hipStream_t stream)
{
    const float* x  = (const float*)d_in[0];
    const float* w1 = (const float*)d_in[1];
    const float* b1 = (const float*)d_in[2];
    const float* w2 = (const float*)d_in[3];
    const float* b2 = (const float*)d_in[4];
    float* out = (float*)d_out;
    __hip_bfloat16* hbf = (__hip_bfloat16*)d_ws;   // 384 KB swizzled h

    gen_h_kernel<<<dim3(N_DEC * BATCH), dim3(128), 0, stream>>>(x, w1, b1, hbf);

    gen_out_mfma<<<dim3(NXBLK, N_DEC), dim3(256), 0, stream>>>(hbf, w2, b2, out);
}

// Round 8
// 369.531 us; speedup vs baseline: 1.8443x; 1.0089x over previous
//
#include <hip/hip_runtime.h>
#include <hip/hip_bf16.h>

#define N_DEC  24
#define IN_DIM 768
#define HID    128
#define ODIM   99136
#define BATCH  64
#define OTILE  256
#define NXBLK  ((ODIM + OTILE - 1) / OTILE)   // 388 (last block: 64 valid cols)

typedef __attribute__((ext_vector_type(8))) short bf16x8;
typedef __attribute__((ext_vector_type(4))) float f32x4;

static __device__ __forceinline__ short f2bf_bits(float f) {
    union { __hip_bfloat16 b; short s; } u;
    u.b = __float2bfloat16(f);
    return u.s;
}

static __device__ __forceinline__ void gload_lds16(const float* src, float* dst) {
    __builtin_amdgcn_global_load_lds(
        (const __attribute__((address_space(1))) void*)src,
        (__attribute__((address_space(3))) void*)dst, 16, 0, 0);
}

// ---------------- Kernel A ----------------
// h stored bf16 in MFMA-A-fragment swizzled order (validated R3-R6):
// per n, chunk c = (ks*4+mt)*64 + lane holds lane's bf16x8 for a[mt][ks].
__global__ __launch_bounds__(128) void gen_h_kernel(
    const float* __restrict__ x, const float* __restrict__ w1,
    const float* __restrict__ b1, __hip_bfloat16* __restrict__ hswz)
{
    const int nb = blockIdx.x;
    const int n  = nb >> 6;
    const int b  = nb & 63;
    const int t  = threadIdx.x;

    __shared__ float xs[IN_DIM];
    #pragma unroll
    for (int i = 0; i < IN_DIM / 128; ++i)
        xs[t + i * 128] = x[b * IN_DIM + t + i * 128];
    __syncthreads();

    const float* w = w1 + (size_t)n * IN_DIM * HID + t;
    float a0 = 0.f, a1 = 0.f, a2 = 0.f, a3 = 0.f;
    #pragma unroll 4
    for (int i = 0; i < IN_DIM; i += 4) {
        a0 = fmaf(xs[i + 0], w[(size_t)(i + 0) * HID], a0);
        a1 = fmaf(xs[i + 1], w[(size_t)(i + 1) * HID], a1);
        a2 = fmaf(xs[i + 2], w[(size_t)(i + 2) * HID], a2);
        a3 = fmaf(xs[i + 3], w[(size_t)(i + 3) * HID], a3);
    }
    float acc = (a0 + a1) + (a2 + a3) + b1[n * HID + t];
    acc = fmaxf(acc, 0.f);

    const int mt = b >> 4, lr = b & 15;
    const int ks = t >> 5, lg = (t >> 3) & 3, ii = t & 7;
    const size_t idx = (size_t)n * 8192
                     + (size_t)(((ks * 4 + mt) * 64) + lg * 16 + lr) * 8 + ii;
    hswz[idx] = __float2bfloat16(acc);
}

// ---------------- Kernel B ----------------
// out[n][b][o] = h[n][b][:] . w2[n][:][o] + b2[n][o]
// Main loop: R6-verified. 4 waves, private 64-col slices, w2 staged per-wave
// in 32-row chunks, double-buffered, barrier-free, counted vmcnt(8).
// Epilogue (new vs R6): cooperative block transpose -> full-row 1KB
// nontemporal dwordx4 stores.
__global__ __launch_bounds__(256, 2) void gen_out_mfma(
    const __hip_bfloat16* __restrict__ hswz, const float* __restrict__ w2,
    const float* __restrict__ b2, float* __restrict__ out)
{
    const int n    = blockIdx.y;
    const int tid  = threadIdx.x;
    const int wave = tid >> 6;
    const int lane = tid & 63;
    const int lr   = lane & 15;
    const int lg   = lane >> 4;
    const long oblk = (long)blockIdx.x * OTILE;
    const long wcol = oblk + wave * 64;          // wave's column base

    __shared__ float lds[2][4][32][64];          // 64 KB; [buf][wave][row][col]

    const float* w2n = w2 + (size_t)n * HID * ODIM;

    // stage chunk ks (rows ks*32..+31, wave's 64 cols) into lds[buf][wave].
    // inst p: lane l writes byte l*16 at base row 4p -> row 4p+(l>>4), dword (l&15)*4.
    // source col pre-swizzled (G21 both-sides) by ((row>>3)&3)<<3.
    auto stage = [&](int buf, int ks) {
        #pragma unroll
        for (int p = 0; p < 8; ++p) {
            const int r   = 4 * p + lg;
            const int swz = ((r >> 3) & 3) << 3;
            const long col = wcol + ((lr * 4) ^ swz);
            long c = col > (long)ODIM - 4 ? (long)ODIM - 4 : col;
            gload_lds16(w2n + (size_t)(ks * 32 + r) * ODIM + c,
                        &lds[buf][wave][4 * p][0]);
        }
    };

    stage(0, 0);                                 // chunk 0 in flight ASAP

    // ---- A fragments (swizzled h, 1KB coalesced loads, L2-hot)
    const bf16x8* ha = (const bf16x8*)hswz + (size_t)n * 1024 + lane;
    bf16x8 a[4][4];
    #pragma unroll
    for (int mt = 0; mt < 4; ++mt)
        #pragma unroll
        for (int ks = 0; ks < 4; ++ks)
            a[mt][ks] = ha[(ks * 4 + mt) * 64];

    // ---- bias scalars: b2 value for this lane's column in each tt-subtile
    float bias_s[4];
    #pragma unroll
    for (int tt = 0; tt < 4; ++tt) {
        long c = wcol + tt * 16 + lr;
        if (c > (long)ODIM - 1) c = (long)ODIM - 1;
        bias_s[tt] = b2[(size_t)n * ODIM + c];
    }

    f32x4 acc[4][4];
    #pragma unroll
    for (int tt = 0; tt < 4; ++tt)
        #pragma unroll
        for (int mt = 0; mt < 4; ++mt)
            acc[tt][mt] = f32x4{0.f, 0.f, 0.f, 0.f};

    #pragma unroll
    for (int ks = 0; ks < 4; ++ks) {
        if (ks < 3) {
            stage((ks + 1) & 1, ks + 1);         // next chunk stays in flight
            asm volatile("s_waitcnt vmcnt(8)" ::: "memory");   // chunk ks landed
        } else {
            asm volatile("s_waitcnt vmcnt(0)" ::: "memory");
        }
        __builtin_amdgcn_sched_barrier(0);       // don't hoist ds_read above wait

        const int buf = ks & 1;
        #pragma unroll
        for (int tt = 0; tt < 4; ++tt) {
            const int csw = (tt * 16 + lr) ^ (lg << 3);   // row>>3 == lg for rows lg*8+i
            const float* lp = &lds[buf][wave][lg * 8][csw];
            float bv[8];
            #pragma unroll
            for (int i = 0; i < 8; ++i)
                bv[i] = lp[(size_t)i * 64];
            bf16x8 bf;
            #pragma unroll
            for (int i = 0; i < 8; ++i)
                bf[i] = f2bf_bits(bv[i]);
            #pragma unroll
            for (int mt = 0; mt < 4; ++mt)
                acc[tt][mt] = __builtin_amdgcn_mfma_f32_16x16x32_bf16(
                                  a[mt][ks], bf, acc[tt][mt], 0, 0, 0);
        }
        __builtin_amdgcn_sched_barrier(0);       // pin next stage below these ds_reads
    }

    // ---- cooperative epilogue: block transpose -> full-row 1KB stores.
    __syncthreads();                             // all waves done reading w2 LDS
    float* trs = &lds[0][0][0][0];               // view as [64][256]

    #pragma unroll
    for (int tt = 0; tt < 4; ++tt)
        #pragma unroll
        for (int mt = 0; mt < 4; ++mt)
            #pragma unroll
            for (int r = 0; r < 4; ++r)
                trs[(mt * 16 + lg * 4 + r) * 256 +
                    ((wave * 64 + tt * 16 + lr) ^ (lg << 3))] =
                    acc[tt][mt][r] + bias_s[tt];

    __syncthreads();

    const long gc = oblk + lane * 4;
    const bool ok = gc <= (long)ODIM - 4;
    #pragma unroll
    for (int j = 0; j < 16; ++j) {
        const int R  = wave * 16 + j;
        const int cR = ((j >> 2) & 3) << 3;      // == ((R>>2)&3)<<3
        f32x4 v = *(const f32x4*)&trs[R * 256 + ((lane * 4) ^ cR)];
        if (ok)
            __builtin_nontemporal_store(
                v, (f32x4*)(out + ((size_t)n * BATCH + R) * ODIM + gc));
    }
}

extern "C" void kernel_launch(void* const* d_in, const int* in_sizes, int n_in,
                              void* d_out, int out_size, void* d_ws, size_t ws_size,
                              hipStream_t stream)
{
    const float* x  = (const float*)d_in[0];
    const float* w1 = (const float*)d_in[1];
    const float* b1 = (const float*)d_in[2];
    const float* w2 = (const float*)d_in[3];
    const float* b2 = (const float*)d_in[4];
    float* out = (float*)d_out;
    __hip_bfloat16* hbf = (__hip_bfloat16*)d_ws;   // 384 KB swizzled h

    gen_h_kernel<<<dim3(N_DEC * BATCH), dim3(128), 0, stream>>>(x, w1, b1, hbf);

    gen_out_mfma<<<dim3(NXBLK, N_DEC), dim3(256), 0, stream>>>(hbf, w2, b2, out);
}